// Round 1
// baseline (5863.885 us; speedup 1.0000x reference)
//
#include <hip/hip_runtime.h>
#include <math.h>

#define TWO_PI_F 6.283185307179586f
#define PI_4_F   0.7853981633974483f

struct Tap { int i00, i01, i10, i11; float w00, w01, w10, w11; };

// ---------------------------------------------------------------------------
// Build per-resolution bilinear sampling tables (replicates make_coords +
// the deform_conv sampling-position math from the reference, per (pixel,tap)).
// ---------------------------------------------------------------------------
__global__ void build_table_kernel(Tap* __restrict__ tab, int S) {
    int idx = blockIdx.x * blockDim.x + threadIdx.x;
    int total = S * S * 9;
    if (idx >= total) return;
    int k = idx % 9;
    int p = idx / 9;
    int y = p / S;
    int x = p - y * S;

    float c = 0.5f * (float)S - 0.5f;
    // theta = atan2(gx-cx, gy-cy) mod 2pi, rounded to 1e-4 (round-half-even)
    float theta = atan2f((float)x - c, (float)y - c);
    theta = fmodf(theta, TWO_PI_F);
    if (theta < 0.0f) theta += TWO_PI_F;
    theta = rintf(theta * 10000.0f) / 10000.0f;

    float offy = 0.0f, offx = 0.0f;
    if (k != 4) {
        int m = (k < 4) ? k : (k - 1);
        const float ayt[8] = { 1.f, 1.f,  1.f, 0.f,  0.f, -1.f, -1.f, -1.f };
        const float axt[8] = { 1.f, 0.f, -1.f, 1.f, -1.f,  1.f,  0.f, -1.f };
        float ang = theta + PI_4_F * (float)m;
        offy = cosf(ang) + ayt[m];
        offx = sinf(ang) + axt[m];
    }
    int ky = k / 3, kx = k - ky * 3;
    float py = (float)y - 1.0f + (float)ky + offy;
    float px = (float)x - 1.0f + (float)kx + offx;
    float fy0 = floorf(py), fx0 = floorf(px);
    float wy = py - fy0, wx = px - fx0;
    float fmaxc = (float)(S - 1);

    Tap t;
    {   // (y0, x0)
        float yy = fy0, xx = fx0;
        bool v = (yy >= 0.f) && (yy <= fmaxc) && (xx >= 0.f) && (xx <= fmaxc);
        int yi = (int)fminf(fmaxf(yy, 0.f), fmaxc);
        int xi = (int)fminf(fmaxf(xx, 0.f), fmaxc);
        t.i00 = yi * S + xi;
        t.w00 = v ? (1.f - wy) * (1.f - wx) : 0.f;
    }
    {   // (y0, x0+1)
        float yy = fy0, xx = fx0 + 1.0f;
        bool v = (yy >= 0.f) && (yy <= fmaxc) && (xx >= 0.f) && (xx <= fmaxc);
        int yi = (int)fminf(fmaxf(yy, 0.f), fmaxc);
        int xi = (int)fminf(fmaxf(xx, 0.f), fmaxc);
        t.i01 = yi * S + xi;
        t.w01 = v ? (1.f - wy) * wx : 0.f;
    }
    {   // (y0+1, x0)
        float yy = fy0 + 1.0f, xx = fx0;
        bool v = (yy >= 0.f) && (yy <= fmaxc) && (xx >= 0.f) && (xx <= fmaxc);
        int yi = (int)fminf(fmaxf(yy, 0.f), fmaxc);
        int xi = (int)fminf(fmaxf(xx, 0.f), fmaxc);
        t.i10 = yi * S + xi;
        t.w10 = v ? wy * (1.f - wx) : 0.f;
    }
    {   // (y0+1, x0+1)
        float yy = fy0 + 1.0f, xx = fx0 + 1.0f;
        bool v = (yy >= 0.f) && (yy <= fmaxc) && (xx >= 0.f) && (xx <= fmaxc);
        int yi = (int)fminf(fmaxf(yy, 0.f), fmaxc);
        int xi = (int)fminf(fmaxf(xx, 0.f), fmaxc);
        t.i11 = yi * S + xi;
        t.w11 = v ? wy * wx : 0.f;
    }
    tab[idx] = t;
}

// ---------------------------------------------------------------------------
// Fused deform-im2col GEMM conv + ReLU.
// Block: 64 output channels (BM) x 64 pixels (BN), 256 threads, 4x4/thread.
// Loop over input channels; per channel stage 9x64 bilinear samples + 9x64
// weights into LDS, then FMA.
// ---------------------------------------------------------------------------
#define CBN 64
#define CBM 64

__global__ __launch_bounds__(256) void dconv_kernel(
    const float* __restrict__ x, const float* __restrict__ w,
    const Tap* __restrict__ tab, float* __restrict__ out,
    int C, int O, int HW)
{
    __shared__ float4 sTabRaw[CBN * 9 * 2];   // 576 Taps = 18 KB
    __shared__ float  sS[9][CBN];
    __shared__ float  sW[9][CBM];

    const int tid = threadIdx.x;
    const int b  = blockIdx.z;
    const int o0 = blockIdx.y * CBM;
    const int p0 = blockIdx.x * CBN;
    const int C9 = C * 9;

    // stage tap table for this pixel tile (contiguous, coalesced)
    const float4* gt = (const float4*)(tab + (size_t)p0 * 9);
    for (int i = tid; i < CBN * 9 * 2; i += 256) sTabRaw[i] = gt[i];
    const Tap* sTab = (const Tap*)sTabRaw;
    __syncthreads();

    float acc[4][4];
#pragma unroll
    for (int i = 0; i < 4; ++i)
#pragma unroll
        for (int j = 0; j < 4; ++j) acc[i][j] = 0.f;

    const int to = tid >> 4;   // 0..15 -> output-channel sub-tile
    const int tn = tid & 15;   // 0..15 -> pixel sub-tile

    const float* xb = x + (size_t)b * C * HW;

    for (int c = 0; c < C; ++c) {
        const float* xp = xb + (size_t)c * HW;
        // bilinear-sample 9 taps x 64 pixels into LDS
        for (int i = tid; i < 9 * CBN; i += 256) {
            int k = i >> 6;
            int p = i & 63;
            Tap t = sTab[p * 9 + k];
            sS[k][p] = t.w00 * xp[t.i00] + t.w01 * xp[t.i01]
                     + t.w10 * xp[t.i10] + t.w11 * xp[t.i11];
        }
        // stage weights w[o, c, k] -> sW[k][o]
        for (int i = tid; i < 9 * CBM; i += 256) {
            int k = i >> 6;
            int o = i & 63;
            sW[k][o] = w[(size_t)(o0 + o) * C9 + c * 9 + k];
        }
        __syncthreads();
#pragma unroll
        for (int k = 0; k < 9; ++k) {
            float4 wv = *(const float4*)&sW[k][to * 4];
            float4 sv = *(const float4*)&sS[k][tn * 4];
            acc[0][0] += wv.x * sv.x; acc[0][1] += wv.x * sv.y; acc[0][2] += wv.x * sv.z; acc[0][3] += wv.x * sv.w;
            acc[1][0] += wv.y * sv.x; acc[1][1] += wv.y * sv.y; acc[1][2] += wv.y * sv.z; acc[1][3] += wv.y * sv.w;
            acc[2][0] += wv.z * sv.x; acc[2][1] += wv.z * sv.y; acc[2][2] += wv.z * sv.z; acc[2][3] += wv.z * sv.w;
            acc[3][0] += wv.w * sv.x; acc[3][1] += wv.w * sv.y; acc[3][2] += wv.w * sv.z; acc[3][3] += wv.w * sv.w;
        }
        __syncthreads();
    }

    // epilogue: ReLU + store (pixels contiguous -> float4)
#pragma unroll
    for (int i = 0; i < 4; ++i) {
        int o = o0 + to * 4 + i;
        float* op = out + ((size_t)b * O + o) * HW + p0 + tn * 4;
        float4 v;
        v.x = fmaxf(acc[i][0], 0.f);
        v.y = fmaxf(acc[i][1], 0.f);
        v.z = fmaxf(acc[i][2], 0.f);
        v.w = fmaxf(acc[i][3], 0.f);
        *(float4*)op = v;
    }
}

// ---------------------------------------------------------------------------
// 2x2 maxpool (input already ReLU'd)
// ---------------------------------------------------------------------------
__global__ void maxpool_kernel(const float* __restrict__ in, float* __restrict__ out,
                               int H, int W, int total)
{
    int idx = blockIdx.x * blockDim.x + threadIdx.x;
    if (idx >= total) return;
    int W2 = W >> 1, H2 = H >> 1;
    int x2 = idx % W2;
    int t  = idx / W2;
    int y2 = t % H2;
    t /= H2;            // t = b*C + c
    const float* p = in + ((size_t)t * H + 2 * y2) * W + 2 * x2;
    out[idx] = fmaxf(fmaxf(p[0], p[1]), fmaxf(p[W], p[W + 1]));
}

// ---------------------------------------------------------------------------
// 4x4 average pool -> (B, 512)
// ---------------------------------------------------------------------------
__global__ void avgpool_kernel(const float* __restrict__ in, float* __restrict__ out, int total)
{
    int idx = blockIdx.x * blockDim.x + threadIdx.x;
    if (idx >= total) return;
    const float* p = in + (size_t)idx * 16;
    float s = 0.f;
#pragma unroll
    for (int i = 0; i < 16; ++i) s += p[i];
    out[idx] = s * (1.0f / 16.0f);
}

// ---------------------------------------------------------------------------
// FC: out[b,o] = relu?(dot(x[b,:], w[o,:]) + bias[o]).  One block per o.
// ---------------------------------------------------------------------------
__global__ __launch_bounds__(256) void fc_kernel(
    const float* __restrict__ x, const float* __restrict__ w,
    const float* __restrict__ bias, float* __restrict__ out,
    int K, int O, int relu)
{
    int o = blockIdx.x;
    float acc[8] = {0.f,0.f,0.f,0.f,0.f,0.f,0.f,0.f};
    const float* wr = w + (size_t)o * K;
    for (int k = threadIdx.x; k < K; k += 256) {
        float wv = wr[k];
#pragma unroll
        for (int b = 0; b < 8; ++b) acc[b] += wv * x[(size_t)b * K + k];
    }
    __shared__ float red[8][256];
#pragma unroll
    for (int b = 0; b < 8; ++b) red[b][threadIdx.x] = acc[b];
    __syncthreads();
    for (int s = 128; s > 0; s >>= 1) {
        if (threadIdx.x < s) {
#pragma unroll
            for (int b = 0; b < 8; ++b) red[b][threadIdx.x] += red[b][threadIdx.x + s];
        }
        __syncthreads();
    }
    if (threadIdx.x < 8) {
        float v = red[threadIdx.x][0] + bias[o];
        if (relu) v = fmaxf(v, 0.f);
        out[(size_t)threadIdx.x * O + o] = v;
    }
}

// ---------------------------------------------------------------------------
// Host orchestration
// ---------------------------------------------------------------------------
extern "C" void kernel_launch(void* const* d_in, const int* in_sizes, int n_in,
                              void* d_out, int out_size, void* d_ws, size_t ws_size,
                              hipStream_t stream) {
    const float* x    = (const float*)d_in[0];
    const float* w11  = (const float*)d_in[1];
    const float* w12  = (const float*)d_in[2];
    const float* w21  = (const float*)d_in[3];
    const float* w22  = (const float*)d_in[4];
    const float* w31  = (const float*)d_in[5];
    const float* w32  = (const float*)d_in[6];
    const float* w33  = (const float*)d_in[7];
    const float* w41  = (const float*)d_in[8];
    const float* w42  = (const float*)d_in[9];
    const float* w43  = (const float*)d_in[10];
    const float* w51  = (const float*)d_in[11];
    const float* w52  = (const float*)d_in[12];
    const float* w53  = (const float*)d_in[13];
    const float* fc1w = (const float*)d_in[14];
    const float* fc1b = (const float*)d_in[15];
    const float* fc2w = (const float*)d_in[16];
    const float* fc2b = (const float*)d_in[17];
    const float* fc3w = (const float*)d_in[18];
    const float* fc3b = (const float*)d_in[19];
    float* out = (float*)d_out;

    char* ws = (char*)d_ws;
    auto alloc = [&](size_t bytes) -> char* {
        char* p = ws;
        ws += (bytes + 255) & ~(size_t)255;
        return p;
    };

    Tap* tab128 = (Tap*)alloc((size_t)128 * 128 * 9 * sizeof(Tap));
    Tap* tab64  = (Tap*)alloc((size_t)64 * 64 * 9 * sizeof(Tap));
    Tap* tab32  = (Tap*)alloc((size_t)32 * 32 * 9 * sizeof(Tap));
    Tap* tab16  = (Tap*)alloc((size_t)16 * 16 * 9 * sizeof(Tap));
    Tap* tab8   = (Tap*)alloc((size_t)8 * 8 * 9 * sizeof(Tap));
    float* actA = (float*)alloc((size_t)8 * 64 * 128 * 128 * sizeof(float));
    float* actB = (float*)alloc((size_t)8 * 64 * 128 * 128 * sizeof(float));
    float* pooled = (float*)alloc((size_t)8 * 512 * sizeof(float));
    float* fcb1 = (float*)alloc((size_t)8 * 4096 * sizeof(float));
    float* fcb2 = (float*)alloc((size_t)8 * 4096 * sizeof(float));

    // build sampling tables
    {
        int sizes[5] = {128, 64, 32, 16, 8};
        Tap* tabs[5] = {tab128, tab64, tab32, tab16, tab8};
        for (int i = 0; i < 5; ++i) {
            int total = sizes[i] * sizes[i] * 9;
            build_table_kernel<<<(total + 255) / 256, 256, 0, stream>>>(tabs[i], sizes[i]);
        }
    }

    auto conv = [&](const float* in, const float* wgt, Tap* tab, float* o,
                    int C, int O, int S) {
        int HW = S * S;
        dim3 grid(HW / CBN, O / CBM, 8);
        dconv_kernel<<<grid, 256, 0, stream>>>(in, wgt, tab, o, C, O, HW);
    };
    auto pool = [&](const float* in, float* o, int C, int H) {
        int total = 8 * C * (H / 2) * (H / 2);
        maxpool_kernel<<<(total + 255) / 256, 256, 0, stream>>>(in, o, H, H, total);
    };

    conv(x,    w11, tab128, actA, 3,   64,  128);
    conv(actA, w12, tab128, actB, 64,  64,  128);
    pool(actB, actA, 64, 128);
    conv(actA, w21, tab64,  actB, 64,  128, 64);
    conv(actB, w22, tab64,  actA, 128, 128, 64);
    pool(actA, actB, 128, 64);
    conv(actB, w31, tab32,  actA, 128, 256, 32);
    conv(actA, w32, tab32,  actB, 256, 256, 32);
    conv(actB, w33, tab32,  actA, 256, 256, 32);
    pool(actA, actB, 256, 32);
    conv(actB, w41, tab16,  actA, 256, 512, 16);
    conv(actA, w42, tab16,  actB, 512, 512, 16);
    conv(actB, w43, tab16,  actA, 512, 512, 16);
    pool(actA, actB, 512, 16);
    conv(actB, w51, tab8,   actA, 512, 512, 8);
    conv(actA, w52, tab8,   actB, 512, 512, 8);
    conv(actB, w53, tab8,   actA, 512, 512, 8);
    pool(actA, actB, 512, 8);

    avgpool_kernel<<<(4096 + 255) / 256, 256, 0, stream>>>(actB, pooled, 8 * 512);

    fc_kernel<<<4096, 256, 0, stream>>>(pooled, fc1w, fc1b, fcb1, 512,  4096, 1);
    fc_kernel<<<4096, 256, 0, stream>>>(fcb1,   fc2w, fc2b, fcb2, 4096, 4096, 1);
    fc_kernel<<<30,   256, 0, stream>>>(fcb2,   fc3w, fc3b, out,  4096, 30,   0);
}

// Round 2
// 2831.709 us; speedup vs baseline: 2.0708x; 2.0708x over previous
//
#include <hip/hip_runtime.h>
#include <math.h>

#define TWO_PI_F 6.283185307179586f
#define PI_4_F   0.7853981633974483f

struct Tap { int i00, i01, i10, i11; float w00, w01, w10, w11; };

// ---------------------------------------------------------------------------
// Build per-resolution bilinear sampling tables (replicates make_coords +
// the deform_conv sampling-position math from the reference, per (pixel,tap)).
// ---------------------------------------------------------------------------
__global__ void build_table_kernel(Tap* __restrict__ tab, int S) {
    int idx = blockIdx.x * blockDim.x + threadIdx.x;
    int total = S * S * 9;
    if (idx >= total) return;
    int k = idx % 9;
    int p = idx / 9;
    int y = p / S;
    int x = p - y * S;

    float c = 0.5f * (float)S - 0.5f;
    float theta = atan2f((float)x - c, (float)y - c);
    theta = fmodf(theta, TWO_PI_F);
    if (theta < 0.0f) theta += TWO_PI_F;
    theta = rintf(theta * 10000.0f) / 10000.0f;

    float offy = 0.0f, offx = 0.0f;
    if (k != 4) {
        int m = (k < 4) ? k : (k - 1);
        const float ayt[8] = { 1.f, 1.f,  1.f, 0.f,  0.f, -1.f, -1.f, -1.f };
        const float axt[8] = { 1.f, 0.f, -1.f, 1.f, -1.f,  1.f,  0.f, -1.f };
        float ang = theta + PI_4_F * (float)m;
        offy = cosf(ang) + ayt[m];
        offx = sinf(ang) + axt[m];
    }
    int ky = k / 3, kx = k - ky * 3;
    float py = (float)y - 1.0f + (float)ky + offy;
    float px = (float)x - 1.0f + (float)kx + offx;
    float fy0 = floorf(py), fx0 = floorf(px);
    float wy = py - fy0, wx = px - fx0;
    float fmaxc = (float)(S - 1);

    Tap t;
    {
        float yy = fy0, xx = fx0;
        bool v = (yy >= 0.f) && (yy <= fmaxc) && (xx >= 0.f) && (xx <= fmaxc);
        int yi = (int)fminf(fmaxf(yy, 0.f), fmaxc);
        int xi = (int)fminf(fmaxf(xx, 0.f), fmaxc);
        t.i00 = yi * S + xi;
        t.w00 = v ? (1.f - wy) * (1.f - wx) : 0.f;
    }
    {
        float yy = fy0, xx = fx0 + 1.0f;
        bool v = (yy >= 0.f) && (yy <= fmaxc) && (xx >= 0.f) && (xx <= fmaxc);
        int yi = (int)fminf(fmaxf(yy, 0.f), fmaxc);
        int xi = (int)fminf(fmaxf(xx, 0.f), fmaxc);
        t.i01 = yi * S + xi;
        t.w01 = v ? (1.f - wy) * wx : 0.f;
    }
    {
        float yy = fy0 + 1.0f, xx = fx0;
        bool v = (yy >= 0.f) && (yy <= fmaxc) && (xx >= 0.f) && (xx <= fmaxc);
        int yi = (int)fminf(fmaxf(yy, 0.f), fmaxc);
        int xi = (int)fminf(fmaxf(xx, 0.f), fmaxc);
        t.i10 = yi * S + xi;
        t.w10 = v ? wy * (1.f - wx) : 0.f;
    }
    {
        float yy = fy0 + 1.0f, xx = fx0 + 1.0f;
        bool v = (yy >= 0.f) && (yy <= fmaxc) && (xx >= 0.f) && (xx <= fmaxc);
        int yi = (int)fminf(fmaxf(yy, 0.f), fmaxc);
        int xi = (int)fminf(fmaxf(xx, 0.f), fmaxc);
        t.i11 = yi * S + xi;
        t.w11 = v ? wy * wx : 0.f;
    }
    tab[idx] = t;
}

// ---------------------------------------------------------------------------
// Fused deform-im2col GEMM conv, with input-channel K-split across blocks.
// Block: 64 output channels x 64 pixels, 256 threads, 4x4/thread.
// blockIdx.z encodes (batch, chunk). nChunks==1 -> direct ReLU store to out;
// else store partial (no ReLU) to part[chunk][b][o][hw]; reduce kernel sums.
// ---------------------------------------------------------------------------
#define CBN 64
#define CBM 64

__global__ __launch_bounds__(256) void dconv_kernel(
    const float* __restrict__ x, const float* __restrict__ w,
    const Tap* __restrict__ tab, float* __restrict__ out,
    float* __restrict__ part,
    int C, int O, int HW, int Cchunk, int nChunks)
{
    __shared__ float4 sTabRaw[CBN * 9 * 2];   // 576 Taps = 18 KB
    __shared__ float  sS[9][CBN];
    __shared__ float  sW[9][CBM];

    const int tid = threadIdx.x;
    const int bz = blockIdx.z;
    const int b     = bz / nChunks;
    const int chunk = bz - b * nChunks;
    const int o0 = blockIdx.y * CBM;
    const int p0 = blockIdx.x * CBN;
    const int C9 = C * 9;
    const int c0 = chunk * Cchunk;
    const int c1 = min(c0 + Cchunk, C);

    // stage tap table for this pixel tile (contiguous, coalesced)
    const float4* gt = (const float4*)(tab + (size_t)p0 * 9);
    for (int i = tid; i < CBN * 9 * 2; i += 256) sTabRaw[i] = gt[i];
    const Tap* sTab = (const Tap*)sTabRaw;
    __syncthreads();

    float acc[4][4];
#pragma unroll
    for (int i = 0; i < 4; ++i)
#pragma unroll
        for (int j = 0; j < 4; ++j) acc[i][j] = 0.f;

    const int to = tid >> 4;   // 0..15 -> output-channel sub-tile
    const int tn = tid & 15;   // 0..15 -> pixel sub-tile

    const float* xb = x + (size_t)b * C * HW;

    for (int c = c0; c < c1; ++c) {
        const float* xp = xb + (size_t)c * HW;
        for (int i = tid; i < 9 * CBN; i += 256) {
            int k = i >> 6;
            int p = i & 63;
            Tap t = sTab[p * 9 + k];
            sS[k][p] = t.w00 * xp[t.i00] + t.w01 * xp[t.i01]
                     + t.w10 * xp[t.i10] + t.w11 * xp[t.i11];
        }
        for (int i = tid; i < 9 * CBM; i += 256) {
            int k = i >> 6;
            int o = i & 63;
            sW[k][o] = w[(size_t)(o0 + o) * C9 + c * 9 + k];
        }
        __syncthreads();
#pragma unroll
        for (int k = 0; k < 9; ++k) {
            float4 wv = *(const float4*)&sW[k][to * 4];
            float4 sv = *(const float4*)&sS[k][tn * 4];
            acc[0][0] += wv.x * sv.x; acc[0][1] += wv.x * sv.y; acc[0][2] += wv.x * sv.z; acc[0][3] += wv.x * sv.w;
            acc[1][0] += wv.y * sv.x; acc[1][1] += wv.y * sv.y; acc[1][2] += wv.y * sv.z; acc[1][3] += wv.y * sv.w;
            acc[2][0] += wv.z * sv.x; acc[2][1] += wv.z * sv.y; acc[2][2] += wv.z * sv.z; acc[2][3] += wv.z * sv.w;
            acc[3][0] += wv.w * sv.x; acc[3][1] += wv.w * sv.y; acc[3][2] += wv.w * sv.z; acc[3][3] += wv.w * sv.w;
        }
        __syncthreads();
    }

    if (nChunks == 1) {
#pragma unroll
        for (int i = 0; i < 4; ++i) {
            int o = o0 + to * 4 + i;
            float* op = out + ((size_t)b * O + o) * HW + p0 + tn * 4;
            float4 v;
            v.x = fmaxf(acc[i][0], 0.f);
            v.y = fmaxf(acc[i][1], 0.f);
            v.z = fmaxf(acc[i][2], 0.f);
            v.w = fmaxf(acc[i][3], 0.f);
            *(float4*)op = v;
        }
    } else {
        float* pb = part + (size_t)chunk * 8 * O * HW;
#pragma unroll
        for (int i = 0; i < 4; ++i) {
            int o = o0 + to * 4 + i;
            float* op = pb + ((size_t)b * O + o) * HW + p0 + tn * 4;
            float4 v;
            v.x = acc[i][0]; v.y = acc[i][1]; v.z = acc[i][2]; v.w = acc[i][3];
            *(float4*)op = v;
        }
    }
}

// sum partial chunks + ReLU
__global__ void reduce_relu_kernel(const float* __restrict__ part,
                                   float* __restrict__ out,
                                   int per, int nChunks)
{
    int idx = blockIdx.x * blockDim.x + threadIdx.x;
    if (idx >= per) return;
    float s = 0.f;
    for (int ch = 0; ch < nChunks; ++ch) s += part[(size_t)ch * per + idx];
    out[idx] = fmaxf(s, 0.f);
}

// ---------------------------------------------------------------------------
// 2x2 maxpool (input already ReLU'd)
// ---------------------------------------------------------------------------
__global__ void maxpool_kernel(const float* __restrict__ in, float* __restrict__ out,
                               int H, int W, int total)
{
    int idx = blockIdx.x * blockDim.x + threadIdx.x;
    if (idx >= total) return;
    int W2 = W >> 1, H2 = H >> 1;
    int x2 = idx % W2;
    int t  = idx / W2;
    int y2 = t % H2;
    t /= H2;
    const float* p = in + ((size_t)t * H + 2 * y2) * W + 2 * x2;
    out[idx] = fmaxf(fmaxf(p[0], p[1]), fmaxf(p[W], p[W + 1]));
}

__global__ void avgpool_kernel(const float* __restrict__ in, float* __restrict__ out, int total)
{
    int idx = blockIdx.x * blockDim.x + threadIdx.x;
    if (idx >= total) return;
    const float* p = in + (size_t)idx * 16;
    float s = 0.f;
#pragma unroll
    for (int i = 0; i < 16; ++i) s += p[i];
    out[idx] = s * (1.0f / 16.0f);
}

__global__ __launch_bounds__(256) void fc_kernel(
    const float* __restrict__ x, const float* __restrict__ w,
    const float* __restrict__ bias, float* __restrict__ out,
    int K, int O, int relu)
{
    int o = blockIdx.x;
    float acc[8] = {0.f,0.f,0.f,0.f,0.f,0.f,0.f,0.f};
    const float* wr = w + (size_t)o * K;
    for (int k = threadIdx.x; k < K; k += 256) {
        float wv = wr[k];
#pragma unroll
        for (int b = 0; b < 8; ++b) acc[b] += wv * x[(size_t)b * K + k];
    }
    __shared__ float red[8][256];
#pragma unroll
    for (int b = 0; b < 8; ++b) red[b][threadIdx.x] = acc[b];
    __syncthreads();
    for (int s = 128; s > 0; s >>= 1) {
        if (threadIdx.x < s) {
#pragma unroll
            for (int b = 0; b < 8; ++b) red[b][threadIdx.x] += red[b][threadIdx.x + s];
        }
        __syncthreads();
    }
    if (threadIdx.x < 8) {
        float v = red[threadIdx.x][0] + bias[o];
        if (relu) v = fmaxf(v, 0.f);
        out[(size_t)threadIdx.x * O + o] = v;
    }
}

// ---------------------------------------------------------------------------
// Host orchestration
// ---------------------------------------------------------------------------
extern "C" void kernel_launch(void* const* d_in, const int* in_sizes, int n_in,
                              void* d_out, int out_size, void* d_ws, size_t ws_size,
                              hipStream_t stream) {
    const float* x    = (const float*)d_in[0];
    const float* w11  = (const float*)d_in[1];
    const float* w12  = (const float*)d_in[2];
    const float* w21  = (const float*)d_in[3];
    const float* w22  = (const float*)d_in[4];
    const float* w31  = (const float*)d_in[5];
    const float* w32  = (const float*)d_in[6];
    const float* w33  = (const float*)d_in[7];
    const float* w41  = (const float*)d_in[8];
    const float* w42  = (const float*)d_in[9];
    const float* w43  = (const float*)d_in[10];
    const float* w51  = (const float*)d_in[11];
    const float* w52  = (const float*)d_in[12];
    const float* w53  = (const float*)d_in[13];
    const float* fc1w = (const float*)d_in[14];
    const float* fc1b = (const float*)d_in[15];
    const float* fc2w = (const float*)d_in[16];
    const float* fc2b = (const float*)d_in[17];
    const float* fc3w = (const float*)d_in[18];
    const float* fc3b = (const float*)d_in[19];
    float* out = (float*)d_out;

    char* ws = (char*)d_ws;
    auto alloc = [&](size_t bytes) -> char* {
        char* p = ws;
        ws += (bytes + 255) & ~(size_t)255;
        return p;
    };

    Tap* tab128 = (Tap*)alloc((size_t)128 * 128 * 9 * sizeof(Tap));
    Tap* tab64  = (Tap*)alloc((size_t)64 * 64 * 9 * sizeof(Tap));
    Tap* tab32  = (Tap*)alloc((size_t)32 * 32 * 9 * sizeof(Tap));
    Tap* tab16  = (Tap*)alloc((size_t)16 * 16 * 9 * sizeof(Tap));
    Tap* tab8   = (Tap*)alloc((size_t)8 * 8 * 9 * sizeof(Tap));
    float* actA = (float*)alloc((size_t)8 * 64 * 128 * 128 * sizeof(float));
    float* actB = (float*)alloc((size_t)8 * 64 * 128 * 128 * sizeof(float));
    float* partial = (float*)alloc((size_t)16 * 8 * 512 * 64 * sizeof(float)); // 16.8 MB, max of all chunked convs
    float* pooled = (float*)alloc((size_t)8 * 512 * sizeof(float));
    float* fcb1 = (float*)alloc((size_t)8 * 4096 * sizeof(float));
    float* fcb2 = (float*)alloc((size_t)8 * 4096 * sizeof(float));

    {
        int sizes[5] = {128, 64, 32, 16, 8};
        Tap* tabs[5] = {tab128, tab64, tab32, tab16, tab8};
        for (int i = 0; i < 5; ++i) {
            int total = sizes[i] * sizes[i] * 9;
            build_table_kernel<<<(total + 255) / 256, 256, 0, stream>>>(tabs[i], sizes[i]);
        }
    }

    // nChunks chosen so each conv launches >= ~1024 blocks
    auto conv = [&](const float* in, const float* wgt, Tap* tab, float* o,
                    int C, int O, int S, int nChunks) {
        int HW = S * S;
        int Cchunk = (C + nChunks - 1) / nChunks;
        dim3 grid(HW / CBN, O / CBM, 8 * nChunks);
        dconv_kernel<<<grid, 256, 0, stream>>>(in, wgt, tab, o, partial,
                                               C, O, HW, Cchunk, nChunks);
        if (nChunks > 1) {
            int per = 8 * O * HW;
            reduce_relu_kernel<<<(per + 255) / 256, 256, 0, stream>>>(partial, o, per, nChunks);
        }
    };
    auto pool = [&](const float* in, float* o, int C, int H) {
        int total = 8 * C * (H / 2) * (H / 2);
        maxpool_kernel<<<(total + 255) / 256, 256, 0, stream>>>(in, o, H, H, total);
    };

    conv(x,    w11, tab128, actA, 3,   64,  128, 1);
    conv(actA, w12, tab128, actB, 64,  64,  128, 1);
    pool(actB, actA, 64, 128);
    conv(actA, w21, tab64,  actB, 64,  128, 64, 1);
    conv(actB, w22, tab64,  actA, 128, 128, 64, 1);
    pool(actA, actB, 128, 64);
    conv(actB, w31, tab32,  actA, 128, 256, 32, 2);
    conv(actA, w32, tab32,  actB, 256, 256, 32, 2);
    conv(actB, w33, tab32,  actA, 256, 256, 32, 2);
    pool(actA, actB, 256, 32);
    conv(actB, w41, tab16,  actA, 256, 512, 16, 4);
    conv(actA, w42, tab16,  actB, 512, 512, 16, 4);
    conv(actB, w43, tab16,  actA, 512, 512, 16, 4);
    pool(actA, actB, 512, 16);
    conv(actB, w51, tab8,   actA, 512, 512, 8, 16);
    conv(actA, w52, tab8,   actB, 512, 512, 8, 16);
    conv(actB, w53, tab8,   actA, 512, 512, 8, 16);
    pool(actA, actB, 512, 8);

    avgpool_kernel<<<(4096 + 255) / 256, 256, 0, stream>>>(actB, pooled, 8 * 512);

    fc_kernel<<<4096, 256, 0, stream>>>(pooled, fc1w, fc1b, fcb1, 512,  4096, 1);
    fc_kernel<<<4096, 256, 0, stream>>>(fcb1,   fc2w, fc2b, fcb2, 4096, 4096, 1);
    fc_kernel<<<30,   256, 0, stream>>>(fcb2,   fc3w, fc3b, out,  4096, 30,   0);
}

// Round 3
// 1614.899 us; speedup vs baseline: 3.6311x; 1.7535x over previous
//
#include <hip/hip_runtime.h>
#include <math.h>

#define TWO_PI_F 6.283185307179586f
#define PI_4_F   0.7853981633974483f

typedef __attribute__((ext_vector_type(8))) short short8;
typedef __attribute__((ext_vector_type(4))) float f32x4;

struct Tap { int i00, i01, i10, i11; float w00, w01, w10, w11; };

static __device__ __forceinline__ unsigned short f2bf(float f) {
    unsigned u = __builtin_bit_cast(unsigned, f);
    u = (u + 0x7fffu + ((u >> 16) & 1u)) >> 16;
    return (unsigned short)u;
}

// ---------------------------------------------------------------------------
// Build per-resolution bilinear sampling tables (replicates make_coords +
// deform_conv sampling math). Exact vs reference (round-1 absmax 0.0).
// ---------------------------------------------------------------------------
__global__ void build_table_kernel(Tap* __restrict__ tab, int S) {
    int idx = blockIdx.x * blockDim.x + threadIdx.x;
    int total = S * S * 9;
    if (idx >= total) return;
    int k = idx % 9;
    int p = idx / 9;
    int y = p / S;
    int x = p - y * S;

    float c = 0.5f * (float)S - 0.5f;
    float theta = atan2f((float)x - c, (float)y - c);
    theta = fmodf(theta, TWO_PI_F);
    if (theta < 0.0f) theta += TWO_PI_F;
    theta = rintf(theta * 10000.0f) / 10000.0f;

    float offy = 0.0f, offx = 0.0f;
    if (k != 4) {
        int m = (k < 4) ? k : (k - 1);
        const float ayt[8] = { 1.f, 1.f,  1.f, 0.f,  0.f, -1.f, -1.f, -1.f };
        const float axt[8] = { 1.f, 0.f, -1.f, 1.f, -1.f,  1.f,  0.f, -1.f };
        float ang = theta + PI_4_F * (float)m;
        offy = cosf(ang) + ayt[m];
        offx = sinf(ang) + axt[m];
    }
    int ky = k / 3, kx = k - ky * 3;
    float py = (float)y - 1.0f + (float)ky + offy;
    float px = (float)x - 1.0f + (float)kx + offx;
    float fy0 = floorf(py), fx0 = floorf(px);
    float wy = py - fy0, wx = px - fx0;
    float fmaxc = (float)(S - 1);

    Tap t;
    {
        float yy = fy0, xx = fx0;
        bool v = (yy >= 0.f) && (yy <= fmaxc) && (xx >= 0.f) && (xx <= fmaxc);
        int yi = (int)fminf(fmaxf(yy, 0.f), fmaxc);
        int xi = (int)fminf(fmaxf(xx, 0.f), fmaxc);
        t.i00 = yi * S + xi;
        t.w00 = v ? (1.f - wy) * (1.f - wx) : 0.f;
    }
    {
        float yy = fy0, xx = fx0 + 1.0f;
        bool v = (yy >= 0.f) && (yy <= fmaxc) && (xx >= 0.f) && (xx <= fmaxc);
        int yi = (int)fminf(fmaxf(yy, 0.f), fmaxc);
        int xi = (int)fminf(fmaxf(xx, 0.f), fmaxc);
        t.i01 = yi * S + xi;
        t.w01 = v ? (1.f - wy) * wx : 0.f;
    }
    {
        float yy = fy0 + 1.0f, xx = fx0;
        bool v = (yy >= 0.f) && (yy <= fmaxc) && (xx >= 0.f) && (xx <= fmaxc);
        int yi = (int)fminf(fmaxf(yy, 0.f), fmaxc);
        int xi = (int)fminf(fmaxf(xx, 0.f), fmaxc);
        t.i10 = yi * S + xi;
        t.w10 = v ? wy * (1.f - wx) : 0.f;
    }
    {
        float yy = fy0 + 1.0f, xx = fx0 + 1.0f;
        bool v = (yy >= 0.f) && (yy <= fmaxc) && (xx >= 0.f) && (xx <= fmaxc);
        int yi = (int)fminf(fmaxf(yy, 0.f), fmaxc);
        int xi = (int)fminf(fmaxf(xx, 0.f), fmaxc);
        t.i11 = yi * S + xi;
        t.w11 = v ? wy * wx : 0.f;
    }
    tab[idx] = t;
}

// ---------------------------------------------------------------------------
// Pack fp32 weights w[O][C][9] -> bf16 MFMA-fragment order wP[kb][o][32],
// K = c*9 + ktap (channel-major), kb = K/32. Requires (C*9) % 32 == 0.
// ---------------------------------------------------------------------------
__global__ void pack_w_kernel(const float* __restrict__ w, unsigned short* __restrict__ wP,
                              int O, int C9, int total) {
    int idx = blockIdx.x * blockDim.x + threadIdx.x;
    if (idx >= total) return;
    int ksub = idx & 31;
    int kbo  = idx >> 5;
    int o  = kbo % O;
    int kb = kbo / O;
    int K = kb * 32 + ksub;
    wP[idx] = f2bf(w[(size_t)o * C9 + K]);
}

// ---------------------------------------------------------------------------
// fp32 conv for conv1_1 only (C=3, 0.3% of FLOPs).
// ---------------------------------------------------------------------------
__global__ __launch_bounds__(256) void dconv_f32_kernel(
    const float* __restrict__ x, const float* __restrict__ w,
    const Tap* __restrict__ tab, float* __restrict__ out,
    int C, int O, int HW)
{
    __shared__ float4 sTabRaw[64 * 9 * 2];
    __shared__ float  sS[9][64];
    __shared__ float  sW[9][64];

    const int tid = threadIdx.x;
    const int b  = blockIdx.z;
    const int o0 = blockIdx.y * 64;
    const int p0 = blockIdx.x * 64;
    const int C9 = C * 9;

    const float4* gt = (const float4*)(tab + (size_t)p0 * 9);
    for (int i = tid; i < 64 * 9 * 2; i += 256) sTabRaw[i] = gt[i];
    const Tap* sTab = (const Tap*)sTabRaw;
    __syncthreads();

    float acc[4][4];
#pragma unroll
    for (int i = 0; i < 4; ++i)
#pragma unroll
        for (int j = 0; j < 4; ++j) acc[i][j] = 0.f;

    const int to = tid >> 4;
    const int tn = tid & 15;
    const float* xb = x + (size_t)b * C * HW;

    for (int c = 0; c < C; ++c) {
        const float* xp = xb + (size_t)c * HW;
        for (int i = tid; i < 9 * 64; i += 256) {
            int k = i >> 6;
            int p = i & 63;
            Tap t = sTab[p * 9 + k];
            sS[k][p] = t.w00 * xp[t.i00] + t.w01 * xp[t.i01]
                     + t.w10 * xp[t.i10] + t.w11 * xp[t.i11];
        }
        for (int i = tid; i < 9 * 64; i += 256) {
            int k = i >> 6;
            int o = i & 63;
            sW[k][o] = w[(size_t)(o0 + o) * C9 + c * 9 + k];
        }
        __syncthreads();
#pragma unroll
        for (int k = 0; k < 9; ++k) {
            float4 wv = *(const float4*)&sW[k][to * 4];
            float4 sv = *(const float4*)&sS[k][tn * 4];
            acc[0][0] += wv.x * sv.x; acc[0][1] += wv.x * sv.y; acc[0][2] += wv.x * sv.z; acc[0][3] += wv.x * sv.w;
            acc[1][0] += wv.y * sv.x; acc[1][1] += wv.y * sv.y; acc[1][2] += wv.y * sv.z; acc[1][3] += wv.y * sv.w;
            acc[2][0] += wv.z * sv.x; acc[2][1] += wv.z * sv.y; acc[2][2] += wv.z * sv.z; acc[2][3] += wv.z * sv.w;
            acc[3][0] += wv.w * sv.x; acc[3][1] += wv.w * sv.y; acc[3][2] += wv.w * sv.z; acc[3][3] += wv.w * sv.w;
        }
        __syncthreads();
    }

#pragma unroll
    for (int i = 0; i < 4; ++i) {
        int o = o0 + to * 4 + i;
        float* op = out + ((size_t)b * O + o) * HW + p0 + tn * 4;
        float4 v;
        v.x = fmaxf(acc[i][0], 0.f);
        v.y = fmaxf(acc[i][1], 0.f);
        v.z = fmaxf(acc[i][2], 0.f);
        v.w = fmaxf(acc[i][3], 0.f);
        *(float4*)op = v;
    }
}

// ---------------------------------------------------------------------------
// MFMA deform-conv. BM x 64px tile, K-split across blocks, 32-channel
// sub-groups: sample -> LDS bf16 -> 9 x mfma_f32_16x16x32_bf16.
// Weights read as A-fragments directly from packed global (L2-resident).
// ---------------------------------------------------------------------------
#define SPITCH 296   // ushorts per px row (K=288 + pad; 592B row, 16B aligned, ~2-way banks)

template<int BM>
__global__ __launch_bounds__(256) void dconv_mfma(
    const float* __restrict__ x, const unsigned short* __restrict__ wP,
    const Tap* __restrict__ tab, float* __restrict__ out,
    float* __restrict__ part,
    int C, int O, int HW, int Cchunk, int nChunks)
{
    __shared__ float4 sTabRaw[64 * 9 * 2];        // 18432 B
    __shared__ unsigned short sS[64 * SPITCH];    // 37888 B

    const int tid  = threadIdx.x;
    const int lane = tid & 63;
    const int wv   = tid >> 6;
    const int bz = blockIdx.z;
    const int b     = bz & 7;
    const int chunk = bz >> 3;
    const int o0 = blockIdx.y * BM;
    const int p0 = blockIdx.x * 64;
    const int c0 = chunk * Cchunk;
    const int nGroups = Cchunk >> 5;

    const int o0w = (BM == 128) ? wv * 32 : (wv >> 1) * 32;
    const int p0w = (BM == 128) ? 0       : (wv & 1) * 32;
    constexpr int MF = 2;
    constexpr int NF = (BM == 128) ? 4 : 2;

    const float4* gt = (const float4*)(tab + (size_t)p0 * 9);
    for (int i = tid; i < 64 * 9 * 2; i += 256) sTabRaw[i] = gt[i];
    const Tap* sTab = (const Tap*)sTabRaw;
    __syncthreads();

    f32x4 acc[MF][NF] = {};

    const float* xb = x + (size_t)b * C * HW;
    const int quad = lane >> 4;
    const int l16  = lane & 15;

    for (int g = 0; g < nGroups; ++g) {
        const int cg = c0 + g * 32;
        // ---- sample 64px x 9taps x 32ch into sS[p][cl*9+kt] (bf16)
        for (int pair = tid; pair < 576; pair += 256) {
            const int p  = pair / 9;
            const int kt = pair - p * 9;
            Tap t = sTab[p * 9 + kt];
            const float* xc = xb + (size_t)cg * HW;
            unsigned short* dst = &sS[p * SPITCH + kt];
#pragma unroll 4
            for (int cl = 0; cl < 32; ++cl) {
                float v = t.w00 * xc[t.i00] + t.w01 * xc[t.i01]
                        + t.w10 * xc[t.i10] + t.w11 * xc[t.i11];
                dst[cl * 9] = f2bf(v);
                xc += HW;
            }
        }
        __syncthreads();
        // ---- 9 MFMA k-steps over K=[cg*9, cg*9+288)
        const int kbBase = (cg * 9) >> 5;
#pragma unroll 3
        for (int kk = 0; kk < 9; ++kk) {
            short8 afr[MF], bfr[NF];
#pragma unroll
            for (int mf = 0; mf < MF; ++mf) {
                int orow = o0 + o0w + mf * 16 + l16;
                afr[mf] = *(const short8*)(wP + (((size_t)(kbBase + kk) * O + orow) << 5) + (quad << 3));
            }
#pragma unroll
            for (int nf = 0; nf < NF; ++nf) {
                int prow = p0w + nf * 16 + l16;
                bfr[nf] = *(const short8*)(&sS[prow * SPITCH + kk * 32 + (quad << 3)]);
            }
#pragma unroll
            for (int mf = 0; mf < MF; ++mf)
#pragma unroll
                for (int nf = 0; nf < NF; ++nf)
                    acc[mf][nf] = __builtin_amdgcn_mfma_f32_16x16x32_bf16(afr[mf], bfr[nf], acc[mf][nf], 0, 0, 0);
        }
        __syncthreads();
    }

    // epilogue: D[m][n] with m=o row=(quad*4+r), n=px col=l16
    if (nChunks == 1) {
#pragma unroll
        for (int mf = 0; mf < MF; ++mf)
#pragma unroll
            for (int nf = 0; nf < NF; ++nf)
#pragma unroll
                for (int r = 0; r < 4; ++r) {
                    int o = o0 + o0w + mf * 16 + (quad << 2) + r;
                    int p = p0 + p0w + nf * 16 + l16;
                    out[((size_t)b * O + o) * HW + p] = fmaxf(acc[mf][nf][r], 0.f);
                }
    } else {
        float* pb = part + (size_t)chunk * 8 * O * HW;
#pragma unroll
        for (int mf = 0; mf < MF; ++mf)
#pragma unroll
            for (int nf = 0; nf < NF; ++nf)
#pragma unroll
                for (int r = 0; r < 4; ++r) {
                    int o = o0 + o0w + mf * 16 + (quad << 2) + r;
                    int p = p0 + p0w + nf * 16 + l16;
                    pb[((size_t)b * O + o) * HW + p] = acc[mf][nf][r];
                }
    }
}

__global__ void reduce_relu_kernel(const float* __restrict__ part,
                                   float* __restrict__ out,
                                   int per, int nChunks)
{
    int idx = blockIdx.x * blockDim.x + threadIdx.x;
    if (idx >= per) return;
    float s = 0.f;
    for (int ch = 0; ch < nChunks; ++ch) s += part[(size_t)ch * per + idx];
    out[idx] = fmaxf(s, 0.f);
}

__global__ void maxpool_kernel(const float* __restrict__ in, float* __restrict__ out,
                               int H, int W, int total)
{
    int idx = blockIdx.x * blockDim.x + threadIdx.x;
    if (idx >= total) return;
    int W2 = W >> 1, H2 = H >> 1;
    int x2 = idx % W2;
    int t  = idx / W2;
    int y2 = t % H2;
    t /= H2;
    const float* p = in + ((size_t)t * H + 2 * y2) * W + 2 * x2;
    out[idx] = fmaxf(fmaxf(p[0], p[1]), fmaxf(p[W], p[W + 1]));
}

__global__ void avgpool_kernel(const float* __restrict__ in, float* __restrict__ out, int total)
{
    int idx = blockIdx.x * blockDim.x + threadIdx.x;
    if (idx >= total) return;
    const float* p = in + (size_t)idx * 16;
    float s = 0.f;
#pragma unroll
    for (int i = 0; i < 16; ++i) s += p[i];
    out[idx] = s * (1.0f / 16.0f);
}

__global__ __launch_bounds__(256) void fc_kernel(
    const float* __restrict__ x, const float* __restrict__ w,
    const float* __restrict__ bias, float* __restrict__ out,
    int K, int O, int relu)
{
    int o = blockIdx.x;
    float acc[8] = {0.f,0.f,0.f,0.f,0.f,0.f,0.f,0.f};
    const float* wr = w + (size_t)o * K;
    for (int k = threadIdx.x; k < K; k += 256) {
        float wv = wr[k];
#pragma unroll
        for (int b = 0; b < 8; ++b) acc[b] += wv * x[(size_t)b * K + k];
    }
    __shared__ float red[8][256];
#pragma unroll
    for (int b = 0; b < 8; ++b) red[b][threadIdx.x] = acc[b];
    __syncthreads();
    for (int s = 128; s > 0; s >>= 1) {
        if (threadIdx.x < s) {
#pragma unroll
            for (int b = 0; b < 8; ++b) red[b][threadIdx.x] += red[b][threadIdx.x + s];
        }
        __syncthreads();
    }
    if (threadIdx.x < 8) {
        float v = red[threadIdx.x][0] + bias[o];
        if (relu) v = fmaxf(v, 0.f);
        out[(size_t)threadIdx.x * O + o] = v;
    }
}

// ---------------------------------------------------------------------------
// Host orchestration
// ---------------------------------------------------------------------------
extern "C" void kernel_launch(void* const* d_in, const int* in_sizes, int n_in,
                              void* d_out, int out_size, void* d_ws, size_t ws_size,
                              hipStream_t stream) {
    const float* x    = (const float*)d_in[0];
    const float* wf[13];
    for (int i = 0; i < 13; ++i) wf[i] = (const float*)d_in[1 + i];
    const float* fc1w = (const float*)d_in[14];
    const float* fc1b = (const float*)d_in[15];
    const float* fc2w = (const float*)d_in[16];
    const float* fc2b = (const float*)d_in[17];
    const float* fc3w = (const float*)d_in[18];
    const float* fc3b = (const float*)d_in[19];
    float* out = (float*)d_out;

    char* ws = (char*)d_ws;
    auto alloc = [&](size_t bytes) -> char* {
        char* p = ws;
        ws += (bytes + 255) & ~(size_t)255;
        return p;
    };

    Tap* tab128 = (Tap*)alloc((size_t)128 * 128 * 9 * sizeof(Tap));
    Tap* tab64  = (Tap*)alloc((size_t)64 * 64 * 9 * sizeof(Tap));
    Tap* tab32  = (Tap*)alloc((size_t)32 * 32 * 9 * sizeof(Tap));
    Tap* tab16  = (Tap*)alloc((size_t)16 * 16 * 9 * sizeof(Tap));
    Tap* tab8   = (Tap*)alloc((size_t)8 * 8 * 9 * sizeof(Tap));
    float* actA = (float*)alloc((size_t)8 * 64 * 128 * 128 * sizeof(float));
    float* actB = (float*)alloc((size_t)8 * 64 * 128 * 128 * sizeof(float));
    float* partial = (float*)alloc((size_t)8 * 512 * 4096 * 2 * sizeof(float)); // 33.6 MB: max chunked partial
    // packed bf16 weights (layers 1..12, conv11 excluded)
    const int Cs[13] = {3, 64, 64, 128, 128, 256, 256, 256, 512, 512, 512, 512, 512};
    const int Os[13] = {64, 64, 128, 128, 256, 256, 256, 512, 512, 512, 512, 512, 512};
    unsigned short* wPk[13];
    wPk[0] = nullptr;
    for (int i = 1; i < 13; ++i)
        wPk[i] = (unsigned short*)alloc((size_t)Os[i] * Cs[i] * 9 * sizeof(unsigned short));
    float* pooled = (float*)alloc((size_t)8 * 512 * sizeof(float));
    float* fcb1 = (float*)alloc((size_t)8 * 4096 * sizeof(float));
    float* fcb2 = (float*)alloc((size_t)8 * 4096 * sizeof(float));

    {
        int sizes[5] = {128, 64, 32, 16, 8};
        Tap* tabs[5] = {tab128, tab64, tab32, tab16, tab8};
        for (int i = 0; i < 5; ++i) {
            int total = sizes[i] * sizes[i] * 9;
            build_table_kernel<<<(total + 255) / 256, 256, 0, stream>>>(tabs[i], sizes[i]);
        }
    }
    for (int i = 1; i < 13; ++i) {
        int total = Os[i] * Cs[i] * 9;
        pack_w_kernel<<<(total + 255) / 256, 256, 0, stream>>>(wf[i], wPk[i], Os[i], Cs[i] * 9, total);
    }

    auto convM = [&](const float* in, const unsigned short* wp, Tap* tab, float* o,
                     int C, int O, int S, int nChunks) {
        int HW = S * S;
        int Cchunk = C / nChunks;
        if (O == 64) {
            dim3 grid(HW / 64, 1, 8 * nChunks);
            dconv_mfma<64><<<grid, 256, 0, stream>>>(in, wp, tab, o, partial, C, O, HW, Cchunk, nChunks);
        } else {
            dim3 grid(HW / 64, O / 128, 8 * nChunks);
            dconv_mfma<128><<<grid, 256, 0, stream>>>(in, wp, tab, o, partial, C, O, HW, Cchunk, nChunks);
        }
        if (nChunks > 1) {
            int per = 8 * O * HW;
            reduce_relu_kernel<<<(per + 255) / 256, 256, 0, stream>>>(partial, o, per, nChunks);
        }
    };
    auto pool = [&](const float* in, float* o, int C, int H) {
        int total = 8 * C * (H / 2) * (H / 2);
        maxpool_kernel<<<(total + 255) / 256, 256, 0, stream>>>(in, o, H, H, total);
    };

    // conv1_1: fp32 path (C=3)
    {
        dim3 grid(128 * 128 / 64, 1, 8);
        dconv_f32_kernel<<<grid, 256, 0, stream>>>(x, wf[0], tab128, actA, 3, 64, 128 * 128);
    }
    convM(actA, wPk[1],  tab128, actB, 64,  64,  128, 1);
    pool(actB, actA, 64, 128);
    convM(actA, wPk[2],  tab64,  actB, 64,  128, 64, 2);
    convM(actB, wPk[3],  tab64,  actA, 128, 128, 64, 2);
    pool(actA, actB, 128, 64);
    convM(actB, wPk[4],  tab32,  actA, 128, 256, 32, 4);
    convM(actA, wPk[5],  tab32,  actB, 256, 256, 32, 4);
    convM(actB, wPk[6],  tab32,  actA, 256, 256, 32, 4);
    pool(actA, actB, 256, 32);
    convM(actB, wPk[7],  tab16,  actA, 256, 512, 16, 8);
    convM(actA, wPk[8],  tab16,  actB, 512, 512, 16, 8);
    convM(actB, wPk[9],  tab16,  actA, 512, 512, 16, 8);
    pool(actA, actB, 512, 16);
    convM(actB, wPk[10], tab8,   actA, 512, 512, 8, 16);
    convM(actA, wPk[11], tab8,   actB, 512, 512, 8, 16);
    convM(actB, wPk[12], tab8,   actA, 512, 512, 8, 16);
    pool(actA, actB, 512, 8);

    avgpool_kernel<<<(4096 + 255) / 256, 256, 0, stream>>>(actB, pooled, 8 * 512);

    fc_kernel<<<4096, 256, 0, stream>>>(pooled, fc1w, fc1b, fcb1, 512,  4096, 1);
    fc_kernel<<<4096, 256, 0, stream>>>(fcb1,   fc2w, fc2b, fcb2, 4096, 4096, 1);
    fc_kernel<<<30,   256, 0, stream>>>(fcb2,   fc3w, fc3b, out,  4096, 30,   0);
}

// Round 4
// 915.018 us; speedup vs baseline: 6.4085x; 1.7649x over previous
//
#include <hip/hip_runtime.h>
#include <math.h>

#define TWO_PI_F 6.283185307179586f
#define PI_4_F   0.7853981633974483f

typedef __attribute__((ext_vector_type(8))) short short8;
typedef __attribute__((ext_vector_type(4))) float f32x4;
typedef __attribute__((ext_vector_type(4))) unsigned short ushort4v;

struct Tap { int i00, i01, i10, i11; float w00, w01, w10, w11; };

static __device__ __forceinline__ unsigned short f2bf(float f) {
    unsigned u = __builtin_bit_cast(unsigned, f);
    u = (u + 0x7fffu + ((u >> 16) & 1u)) >> 16;
    return (unsigned short)u;
}

// ---------------------------------------------------------------------------
// Build per-resolution sampling tables. Writes BOTH AoS (Tap, used by the
// fp32 conv1_1 path) and SoA planes tabT[(kt*8+comp)*HW + p] for the
// coalesced MFMA sampler (comp 0-3: int idx, 4-7: float weight bits).
// ---------------------------------------------------------------------------
__global__ void build_table_kernel(Tap* __restrict__ tab, int* __restrict__ tabT, int S) {
    int idx = blockIdx.x * blockDim.x + threadIdx.x;
    int total = S * S * 9;
    if (idx >= total) return;
    int k = idx % 9;
    int p = idx / 9;
    int y = p / S;
    int x = p - y * S;
    int HW = S * S;

    float c = 0.5f * (float)S - 0.5f;
    float theta = atan2f((float)x - c, (float)y - c);
    theta = fmodf(theta, TWO_PI_F);
    if (theta < 0.0f) theta += TWO_PI_F;
    theta = rintf(theta * 10000.0f) / 10000.0f;

    float offy = 0.0f, offx = 0.0f;
    if (k != 4) {
        int m = (k < 4) ? k : (k - 1);
        const float ayt[8] = { 1.f, 1.f,  1.f, 0.f,  0.f, -1.f, -1.f, -1.f };
        const float axt[8] = { 1.f, 0.f, -1.f, 1.f, -1.f,  1.f,  0.f, -1.f };
        float ang = theta + PI_4_F * (float)m;
        offy = cosf(ang) + ayt[m];
        offx = sinf(ang) + axt[m];
    }
    int ky = k / 3, kx = k - ky * 3;
    float py = (float)y - 1.0f + (float)ky + offy;
    float px = (float)x - 1.0f + (float)kx + offx;
    float fy0 = floorf(py), fx0 = floorf(px);
    float wy = py - fy0, wx = px - fx0;
    float fmaxc = (float)(S - 1);

    Tap t;
    {
        float yy = fy0, xx = fx0;
        bool v = (yy >= 0.f) && (yy <= fmaxc) && (xx >= 0.f) && (xx <= fmaxc);
        int yi = (int)fminf(fmaxf(yy, 0.f), fmaxc);
        int xi = (int)fminf(fmaxf(xx, 0.f), fmaxc);
        t.i00 = yi * S + xi;
        t.w00 = v ? (1.f - wy) * (1.f - wx) : 0.f;
    }
    {
        float yy = fy0, xx = fx0 + 1.0f;
        bool v = (yy >= 0.f) && (yy <= fmaxc) && (xx >= 0.f) && (xx <= fmaxc);
        int yi = (int)fminf(fmaxf(yy, 0.f), fmaxc);
        int xi = (int)fminf(fmaxf(xx, 0.f), fmaxc);
        t.i01 = yi * S + xi;
        t.w01 = v ? (1.f - wy) * wx : 0.f;
    }
    {
        float yy = fy0 + 1.0f, xx = fx0;
        bool v = (yy >= 0.f) && (yy <= fmaxc) && (xx >= 0.f) && (xx <= fmaxc);
        int yi = (int)fminf(fmaxf(yy, 0.f), fmaxc);
        int xi = (int)fminf(fmaxf(xx, 0.f), fmaxc);
        t.i10 = yi * S + xi;
        t.w10 = v ? wy * (1.f - wx) : 0.f;
    }
    {
        float yy = fy0 + 1.0f, xx = fx0 + 1.0f;
        bool v = (yy >= 0.f) && (yy <= fmaxc) && (xx >= 0.f) && (xx <= fmaxc);
        int yi = (int)fminf(fmaxf(yy, 0.f), fmaxc);
        int xi = (int)fminf(fmaxf(xx, 0.f), fmaxc);
        t.i11 = yi * S + xi;
        t.w11 = v ? wy * wx : 0.f;
    }
    tab[idx] = t;

    tabT[(k * 8 + 0) * HW + p] = t.i00;
    tabT[(k * 8 + 1) * HW + p] = t.i01;
    tabT[(k * 8 + 2) * HW + p] = t.i10;
    tabT[(k * 8 + 3) * HW + p] = t.i11;
    tabT[(k * 8 + 4) * HW + p] = __builtin_bit_cast(int, t.w00);
    tabT[(k * 8 + 5) * HW + p] = __builtin_bit_cast(int, t.w01);
    tabT[(k * 8 + 6) * HW + p] = __builtin_bit_cast(int, t.w10);
    tabT[(k * 8 + 7) * HW + p] = __builtin_bit_cast(int, t.w11);
}

// ---------------------------------------------------------------------------
// Pack fp32 weights w[O][C][9] -> bf16 fragment order wP[kb][o][32] with
// TAP-MAJOR K: K = kt*C + c  (kt = K/C, c = K%C). Requires C % 32 == 0.
// ---------------------------------------------------------------------------
__global__ void pack_w_kernel(const float* __restrict__ w, unsigned short* __restrict__ wP,
                              int O, int C, int total) {
    int idx = blockIdx.x * blockDim.x + threadIdx.x;
    if (idx >= total) return;
    int ksub = idx & 31;
    int kbo  = idx >> 5;
    int o  = kbo % O;
    int kb = kbo / O;
    int K = kb * 32 + ksub;
    int kt = K / C;
    int c  = K - kt * C;
    wP[idx] = f2bf(w[((size_t)o * C + c) * 9 + kt]);
}

// ---------------------------------------------------------------------------
// fp32 conv for conv1_1 only (C=3, 0.3% of FLOPs).
// ---------------------------------------------------------------------------
__global__ __launch_bounds__(256) void dconv_f32_kernel(
    const float* __restrict__ x, const float* __restrict__ w,
    const Tap* __restrict__ tab, float* __restrict__ out,
    int C, int O, int HW)
{
    __shared__ float4 sTabRaw[64 * 9 * 2];
    __shared__ float  sS[9][64];
    __shared__ float  sW[9][64];

    const int tid = threadIdx.x;
    const int b  = blockIdx.z;
    const int o0 = blockIdx.y * 64;
    const int p0 = blockIdx.x * 64;
    const int C9 = C * 9;

    const float4* gt = (const float4*)(tab + (size_t)p0 * 9);
    for (int i = tid; i < 64 * 9 * 2; i += 256) sTabRaw[i] = gt[i];
    const Tap* sTab = (const Tap*)sTabRaw;
    __syncthreads();

    float acc[4][4];
#pragma unroll
    for (int i = 0; i < 4; ++i)
#pragma unroll
        for (int j = 0; j < 4; ++j) acc[i][j] = 0.f;

    const int to = tid >> 4;
    const int tn = tid & 15;
    const float* xb = x + (size_t)b * C * HW;

    for (int c = 0; c < C; ++c) {
        const float* xp = xb + (size_t)c * HW;
        for (int i = tid; i < 9 * 64; i += 256) {
            int k = i >> 6;
            int p = i & 63;
            Tap t = sTab[p * 9 + k];
            sS[k][p] = t.w00 * xp[t.i00] + t.w01 * xp[t.i01]
                     + t.w10 * xp[t.i10] + t.w11 * xp[t.i11];
        }
        for (int i = tid; i < 9 * 64; i += 256) {
            int k = i >> 6;
            int o = i & 63;
            sW[k][o] = w[(size_t)(o0 + o) * C9 + c * 9 + k];
        }
        __syncthreads();
#pragma unroll
        for (int k = 0; k < 9; ++k) {
            float4 wv = *(const float4*)&sW[k][to * 4];
            float4 sv = *(const float4*)&sS[k][tn * 4];
            acc[0][0] += wv.x * sv.x; acc[0][1] += wv.x * sv.y; acc[0][2] += wv.x * sv.z; acc[0][3] += wv.x * sv.w;
            acc[1][0] += wv.y * sv.x; acc[1][1] += wv.y * sv.y; acc[1][2] += wv.y * sv.z; acc[1][3] += wv.y * sv.w;
            acc[2][0] += wv.z * sv.x; acc[2][1] += wv.z * sv.y; acc[2][2] += wv.z * sv.z; acc[2][3] += wv.z * sv.w;
            acc[3][0] += wv.w * sv.x; acc[3][1] += wv.w * sv.y; acc[3][2] += wv.w * sv.z; acc[3][3] += wv.w * sv.w;
        }
        __syncthreads();
    }

#pragma unroll
    for (int i = 0; i < 4; ++i) {
        int o = o0 + to * 4 + i;
        float* op = out + ((size_t)b * O + o) * HW + p0 + tn * 4;
        float4 v;
        v.x = fmaxf(acc[i][0], 0.f);
        v.y = fmaxf(acc[i][1], 0.f);
        v.z = fmaxf(acc[i][2], 0.f);
        v.w = fmaxf(acc[i][3], 0.f);
        *(float4*)op = v;
    }
}

// ---------------------------------------------------------------------------
// MFMA deform-conv, coalesced sampler (lane = pixel).
// Tile: BM out-channels x 64 pixels. K-split across blocks.
// Per 32-channel group: wave w samples channels w*8..w*8+7 for all 9 taps,
// lane = pixel -> 4 quasi-coalesced corner gathers per (tap,channel);
// 4 channels packed per ds_write_b64. Then 9 MFMA k-steps (tap-major K).
// ---------------------------------------------------------------------------
#define SPITCH 296   // ushorts per px row (288 + 8 pad; row = 592B, 16B aligned)

template<int BM>
__global__ __launch_bounds__(256, 4) void dconv_mfma(
    const float* __restrict__ x, const unsigned short* __restrict__ wP,
    const int* __restrict__ tabT, float* __restrict__ out,
    float* __restrict__ part,
    int C, int O, int HW, int Cchunk, int nChunks)
{
    __shared__ unsigned short sS[64 * SPITCH];    // 37888 B

    const int tid  = threadIdx.x;
    const int lane = tid & 63;
    const int wv   = tid >> 6;
    const int bz = blockIdx.z;
    const int b     = bz & 7;
    const int chunk = bz >> 3;
    const int o0 = blockIdx.y * BM;
    const int p0 = blockIdx.x * 64;
    const int c0 = chunk * Cchunk;
    const int nGroups = Cchunk >> 5;

    const int o0w = (BM == 128) ? wv * 32 : (wv >> 1) * 32;
    const int p0w = (BM == 128) ? 0       : (wv & 1) * 32;
    constexpr int MF = 2;
    constexpr int NF = (BM == 128) ? 4 : 2;

    f32x4 acc[MF][NF] = {};

    const float* xb = x + (size_t)b * C * HW;
    const int quad = lane >> 4;
    const int l16  = lane & 15;
    const int* tp0 = tabT + p0 + lane;   // lane's pixel column in SoA planes

    for (int g = 0; g < nGroups; ++g) {
        const int cg = c0 + g * 32;                 // chunk-global first channel of group
        const float* xw = xb + (size_t)(cg + wv * 8) * HW;   // wave's first channel plane
        unsigned short* srow = &sS[lane * SPITCH + wv * 8];

        // ---- sample: 9 taps x 8 channels, lane = pixel (coalesced gathers)
        for (int kt = 0; kt < 9; ++kt) {
            const int* tp = tp0 + kt * 8 * HW;
            int   i00 = tp[0];
            int   i01 = tp[HW];
            int   i10 = tp[2 * HW];
            int   i11 = tp[3 * HW];
            float w00 = __builtin_bit_cast(float, tp[4 * HW]);
            float w01 = __builtin_bit_cast(float, tp[5 * HW]);
            float w10 = __builtin_bit_cast(float, tp[6 * HW]);
            float w11 = __builtin_bit_cast(float, tp[7 * HW]);
#pragma unroll
            for (int cq = 0; cq < 2; ++cq) {
                float v[4];
#pragma unroll
                for (int j = 0; j < 4; ++j) {
                    const float* xc = xw + (size_t)(cq * 4 + j) * HW;
                    v[j] = w00 * xc[i00] + w01 * xc[i01]
                         + w10 * xc[i10] + w11 * xc[i11];
                }
                ushort4v pk;
                pk.x = f2bf(v[0]); pk.y = f2bf(v[1]);
                pk.z = f2bf(v[2]); pk.w = f2bf(v[3]);
                *(ushort4v*)(srow + kt * 32 + cq * 4) = pk;
            }
        }
        __syncthreads();

        // ---- 9 MFMA k-steps; K-tile for tap kt is kb = (kt*C + cg)/32
#pragma unroll 3
        for (int kt = 0; kt < 9; ++kt) {
            const int kb = (kt * C + cg) >> 5;
            short8 afr[MF], bfr[NF];
#pragma unroll
            for (int mf = 0; mf < MF; ++mf) {
                int orow = o0 + o0w + mf * 16 + l16;
                afr[mf] = *(const short8*)(wP + (((size_t)kb * O + orow) << 5) + (quad << 3));
            }
#pragma unroll
            for (int nf = 0; nf < NF; ++nf) {
                int prow = p0w + nf * 16 + l16;
                bfr[nf] = *(const short8*)(&sS[prow * SPITCH + kt * 32 + (quad << 3)]);
            }
#pragma unroll
            for (int mf = 0; mf < MF; ++mf)
#pragma unroll
                for (int nf = 0; nf < NF; ++nf)
                    acc[mf][nf] = __builtin_amdgcn_mfma_f32_16x16x32_bf16(afr[mf], bfr[nf], acc[mf][nf], 0, 0, 0);
        }
        __syncthreads();
    }

    // epilogue: D row = quad*4+r (out ch), col = l16 (pixel)
    if (nChunks == 1) {
#pragma unroll
        for (int mf = 0; mf < MF; ++mf)
#pragma unroll
            for (int nf = 0; nf < NF; ++nf)
#pragma unroll
                for (int r = 0; r < 4; ++r) {
                    int o = o0 + o0w + mf * 16 + (quad << 2) + r;
                    int p = p0 + p0w + nf * 16 + l16;
                    out[((size_t)b * O + o) * HW + p] = fmaxf(acc[mf][nf][r], 0.f);
                }
    } else {
        float* pb = part + (size_t)chunk * 8 * O * HW;
#pragma unroll
        for (int mf = 0; mf < MF; ++mf)
#pragma unroll
            for (int nf = 0; nf < NF; ++nf)
#pragma unroll
                for (int r = 0; r < 4; ++r) {
                    int o = o0 + o0w + mf * 16 + (quad << 2) + r;
                    int p = p0 + p0w + nf * 16 + l16;
                    pb[((size_t)b * O + o) * HW + p] = acc[mf][nf][r];
                }
    }
}

// sum partial chunks + ReLU (float4)
__global__ void reduce_relu_kernel(const float* __restrict__ part,
                                   float* __restrict__ out,
                                   int per4, int nChunks)
{
    int idx = blockIdx.x * blockDim.x + threadIdx.x;
    if (idx >= per4) return;
    const float4* p4 = (const float4*)part;
    float4 s = p4[idx];
    for (int ch = 1; ch < nChunks; ++ch) {
        float4 v = p4[(size_t)ch * per4 + idx];
        s.x += v.x; s.y += v.y; s.z += v.z; s.w += v.w;
    }
    float4 r;
    r.x = fmaxf(s.x, 0.f); r.y = fmaxf(s.y, 0.f);
    r.z = fmaxf(s.z, 0.f); r.w = fmaxf(s.w, 0.f);
    ((float4*)out)[idx] = r;
}

__global__ void maxpool_kernel(const float* __restrict__ in, float* __restrict__ out,
                               int H, int W, int total)
{
    int idx = blockIdx.x * blockDim.x + threadIdx.x;
    if (idx >= total) return;
    int W2 = W >> 1, H2 = H >> 1;
    int x2 = idx % W2;
    int t  = idx / W2;
    int y2 = t % H2;
    t /= H2;
    const float* p = in + ((size_t)t * H + 2 * y2) * W + 2 * x2;
    out[idx] = fmaxf(fmaxf(p[0], p[1]), fmaxf(p[W], p[W + 1]));
}

__global__ void avgpool_kernel(const float* __restrict__ in, float* __restrict__ out, int total)
{
    int idx = blockIdx.x * blockDim.x + threadIdx.x;
    if (idx >= total) return;
    const float* p = in + (size_t)idx * 16;
    float s = 0.f;
#pragma unroll
    for (int i = 0; i < 16; ++i) s += p[i];
    out[idx] = s * (1.0f / 16.0f);
}

__global__ __launch_bounds__(256) void fc_kernel(
    const float* __restrict__ x, const float* __restrict__ w,
    const float* __restrict__ bias, float* __restrict__ out,
    int K, int O, int relu)
{
    int o = blockIdx.x;
    float acc[8] = {0.f,0.f,0.f,0.f,0.f,0.f,0.f,0.f};
    const float* wr = w + (size_t)o * K;
    for (int k = threadIdx.x; k < K; k += 256) {
        float wv = wr[k];
#pragma unroll
        for (int b = 0; b < 8; ++b) acc[b] += wv * x[(size_t)b * K + k];
    }
    __shared__ float red[8][256];
#pragma unroll
    for (int b = 0; b < 8; ++b) red[b][threadIdx.x] = acc[b];
    __syncthreads();
    for (int s = 128; s > 0; s >>= 1) {
        if (threadIdx.x < s) {
#pragma unroll
            for (int b = 0; b < 8; ++b) red[b][threadIdx.x] += red[b][threadIdx.x + s];
        }
        __syncthreads();
    }
    if (threadIdx.x < 8) {
        float v = red[threadIdx.x][0] + bias[o];
        if (relu) v = fmaxf(v, 0.f);
        out[(size_t)threadIdx.x * O + o] = v;
    }
}

// ---------------------------------------------------------------------------
// Host orchestration
// ---------------------------------------------------------------------------
extern "C" void kernel_launch(void* const* d_in, const int* in_sizes, int n_in,
                              void* d_out, int out_size, void* d_ws, size_t ws_size,
                              hipStream_t stream) {
    const float* x    = (const float*)d_in[0];
    const float* wf[13];
    for (int i = 0; i < 13; ++i) wf[i] = (const float*)d_in[1 + i];
    const float* fc1w = (const float*)d_in[14];
    const float* fc1b = (const float*)d_in[15];
    const float* fc2w = (const float*)d_in[16];
    const float* fc2b = (const float*)d_in[17];
    const float* fc3w = (const float*)d_in[18];
    const float* fc3b = (const float*)d_in[19];
    float* out = (float*)d_out;

    char* ws = (char*)d_ws;
    auto alloc = [&](size_t bytes) -> char* {
        char* p = ws;
        ws += (bytes + 255) & ~(size_t)255;
        return p;
    };

    const int sizes[5] = {128, 64, 32, 16, 8};
    Tap* tabs[5];
    int* tabTs[5];
    for (int i = 0; i < 5; ++i) {
        int HW = sizes[i] * sizes[i];
        tabs[i]  = (Tap*)alloc((size_t)HW * 9 * sizeof(Tap));
        tabTs[i] = (int*)alloc((size_t)HW * 9 * 8 * sizeof(int));
    }
    float* actA = (float*)alloc((size_t)8 * 64 * 128 * 128 * sizeof(float));
    float* actB = (float*)alloc((size_t)8 * 64 * 128 * 128 * sizeof(float));
    float* partial = (float*)alloc((size_t)8 * 512 * 4096 * 2 * sizeof(float)); // 33.6 MB
    const int Cs[13] = {3, 64, 64, 128, 128, 256, 256, 256, 512, 512, 512, 512, 512};
    const int Os[13] = {64, 64, 128, 128, 256, 256, 256, 512, 512, 512, 512, 512, 512};
    unsigned short* wPk[13];
    wPk[0] = nullptr;
    for (int i = 1; i < 13; ++i)
        wPk[i] = (unsigned short*)alloc((size_t)Os[i] * Cs[i] * 9 * sizeof(unsigned short));
    float* pooled = (float*)alloc((size_t)8 * 512 * sizeof(float));
    float* fcb1 = (float*)alloc((size_t)8 * 4096 * sizeof(float));
    float* fcb2 = (float*)alloc((size_t)8 * 4096 * sizeof(float));

    for (int i = 0; i < 5; ++i) {
        int total = sizes[i] * sizes[i] * 9;
        build_table_kernel<<<(total + 255) / 256, 256, 0, stream>>>(tabs[i], tabTs[i], sizes[i]);
    }
    for (int i = 1; i < 13; ++i) {
        int total = Os[i] * Cs[i] * 9;
        pack_w_kernel<<<(total + 255) / 256, 256, 0, stream>>>(wf[i], wPk[i], Os[i], Cs[i], total);
    }

    auto convM = [&](const float* in, const unsigned short* wp, int* tabT, float* o,
                     int C, int O, int S, int nChunks) {
        int HW = S * S;
        int Cchunk = C / nChunks;
        if (O == 64) {
            dim3 grid(HW / 64, 1, 8 * nChunks);
            dconv_mfma<64><<<grid, 256, 0, stream>>>(in, wp, tabT, o, partial, C, O, HW, Cchunk, nChunks);
        } else {
            dim3 grid(HW / 64, O / 128, 8 * nChunks);
            dconv_mfma<128><<<grid, 256, 0, stream>>>(in, wp, tabT, o, partial, C, O, HW, Cchunk, nChunks);
        }
        if (nChunks > 1) {
            int per4 = 8 * O * HW / 4;
            reduce_relu_kernel<<<(per4 + 255) / 256, 256, 0, stream>>>(partial, o, per4, nChunks);
        }
    };
    auto pool = [&](const float* in, float* o, int C, int H) {
        int total = 8 * C * (H / 2) * (H / 2);
        maxpool_kernel<<<(total + 255) / 256, 256, 0, stream>>>(in, o, H, H, total);
    };

    // conv1_1: fp32 path (C=3)
    {
        dim3 grid(128 * 128 / 64, 1, 8);
        dconv_f32_kernel<<<grid, 256, 0, stream>>>(x, wf[0], tabs[0], actA, 3, 64, 128 * 128);
    }
    convM(actA, wPk[1],  tabTs[0], actB, 64,  64,  128, 1);
    pool(actB, actA, 64, 128);
    convM(actA, wPk[2],  tabTs[1], actB, 64,  128, 64, 2);
    convM(actB, wPk[3],  tabTs[1], actA, 128, 128, 64, 2);
    pool(actA, actB, 128, 64);
    convM(actB, wPk[4],  tabTs[2], actA, 128, 256, 32, 2);
    convM(actA, wPk[5],  tabTs[2], actB, 256, 256, 32, 2);
    convM(actB, wPk[6],  tabTs[2], actA, 256, 256, 32, 2);
    pool(actA, actB, 256, 32);
    convM(actB, wPk[7],  tabTs[3], actA, 256, 512, 16, 4);
    convM(actA, wPk[8],  tabTs[3], actB, 512, 512, 16, 4);
    convM(actB, wPk[9],  tabTs[3], actA, 512, 512, 16, 4);
    pool(actA, actB, 512, 16);
    convM(actB, wPk[10], tabTs[4], actA, 512, 512, 8, 16);
    convM(actA, wPk[11], tabTs[4], actB, 512, 512, 8, 16);
    convM(actB, wPk[12], tabTs[4], actA, 512, 512, 8, 16);
    pool(actA, actB, 512, 8);

    avgpool_kernel<<<(4096 + 255) / 256, 256, 0, stream>>>(actB, pooled, 8 * 512);

    fc_kernel<<<4096, 256, 0, stream>>>(pooled, fc1w, fc1b, fcb1, 512,  4096, 1);
    fc_kernel<<<4096, 256, 0, stream>>>(fcb1,   fc2w, fc2b, fcb2, 4096, 4096, 1);
    fc_kernel<<<30,   256, 0, stream>>>(fcb2,   fc3w, fc3b, out,  4096, 30,   0);
}